// Round 10
// baseline (263.847 us; speedup 1.0000x reference)
//
#include <hip/hip_runtime.h>
#include <cstddef>

#define NN 20000
#define NE 320000

typedef short bf16x8 __attribute__((ext_vector_type(8)));
typedef float f32x4 __attribute__((ext_vector_type(4)));
typedef unsigned short u16;

__device__ __forceinline__ float bf2f(u16 u) {
    unsigned x = ((unsigned)u) << 16;
    return __builtin_bit_cast(float, x);
}
__device__ __forceinline__ u16 f2bf(float f) {
    unsigned x = __builtin_bit_cast(unsigned, f);
    x = (x + 0x7fff + ((x >> 16) & 1)) >> 16;   // round-to-nearest-even
    return (u16)x;
}

// ---------------- edge-index layout detection (low-contention) ----------------
__global__ __launch_bounds__(256) void detect_kernel(const void* __restrict__ edges, int* flag) {
    __shared__ int bad;
    if (threadIdx.x == 0) bad = 0;
    __syncthreads();
    int any = 0;
    for (int i = blockIdx.x * 256 + threadIdx.x; i < NE; i += 64 * 256) {
        long long v = ((const long long*)edges)[i];
        if (v < 0 || v >= NN) any = 1;
    }
    if (any) bad = 1;               // benign LDS race: all write 1
    __syncthreads();
    if (threadIdx.x == 0 && bad) atomicOr(flag, 1);
}

__global__ __launch_bounds__(256) void convert_kernel(const void* __restrict__ edges,
                                                      const int* __restrict__ flag,
                                                      int* __restrict__ src, int* __restrict__ dst,
                                                      int* __restrict__ deg) {
    int i = blockIdx.x * blockDim.x + threadIdx.x;
    if (i >= NE) return;
    int s, d;
    if (*flag) {
        s = ((const int*)edges)[i];
        d = ((const int*)edges)[NE + i];
    } else {
        s = (int)((const long long*)edges)[i];
        d = (int)((const long long*)edges)[NE + i];
    }
    src[i] = s;
    dst[i] = d;
    atomicAdd(&deg[d], 1);
}

// ---------------- parallel exclusive scan (3 phases) ----------------
__global__ __launch_bounds__(256) void scan1_kernel(const int* __restrict__ deg,
                                                    int* __restrict__ incl, int* __restrict__ bsum) {
    __shared__ int buf[256];
    int t = threadIdx.x, i = blockIdx.x * 256 + t;
    int v = (i < NN) ? deg[i] : 0;
    buf[t] = v;
    __syncthreads();
    for (int off = 1; off < 256; off <<= 1) {
        int u = (t >= off) ? buf[t - off] : 0;
        __syncthreads();
        buf[t] += u;
        __syncthreads();
    }
    if (i < NN) incl[i] = buf[t];
    if (t == 255) bsum[blockIdx.x] = buf[255];
}

__global__ __launch_bounds__(256) void scan2_kernel(const int* __restrict__ bsum,
                                                    int* __restrict__ boff) {
    __shared__ int buf[256];
    const int nb = (NN + 255) / 256;   // 79
    int t = threadIdx.x;
    int v = (t < nb) ? bsum[t] : 0;
    buf[t] = v;
    __syncthreads();
    for (int off = 1; off < 256; off <<= 1) {
        int u = (t >= off) ? buf[t - off] : 0;
        __syncthreads();
        buf[t] += u;
        __syncthreads();
    }
    if (t < nb) boff[t] = buf[t] - v;   // exclusive
}

__global__ __launch_bounds__(256) void scan3_kernel(const int* __restrict__ deg,
                                                    const int* __restrict__ incl,
                                                    const int* __restrict__ boff,
                                                    int* __restrict__ rowptr) {
    int i = blockIdx.x * 256 + threadIdx.x;
    if (i < NN) rowptr[i] = boff[i >> 8] + incl[i] - deg[i];
    if (i == NN) rowptr[NN] = NE;
}

// ---------------- CSR fill ----------------
__global__ __launch_bounds__(256) void fill_kernel(const int* __restrict__ src,
                                                   const int* __restrict__ dst,
                                                   const int* __restrict__ rowptr,
                                                   int* __restrict__ cursor,
                                                   int* __restrict__ csr_src) {
    int i = blockIdx.x * blockDim.x + threadIdx.x;
    if (i >= NE) return;
    int d = dst[i];
    int p = atomicAdd(&cursor[d], 1);
    csr_src[rowptr[d] + p] = src[i];
}

// ---------------- fp32 -> bf16 cast ----------------
__global__ __launch_bounds__(256) void cast_kernel(const float* __restrict__ in,
                                                   u16* __restrict__ out, int n4) {
    int i = blockIdx.x * 256 + threadIdx.x;
    if (i >= n4) return;
    float4 v = *(const float4*)(in + (size_t)i * 4);
    ushort4 o;
    o.x = f2bf(v.x); o.y = f2bf(v.y); o.z = f2bf(v.z); o.w = f2bf(v.w);
    *(ushort4*)(out + (size_t)i * 4) = o;
}

// ---------------- fused weight transpose+cast: 9 jobs in one dispatch ----------------
struct WJobs {
    const float* W[9];
    u16* WT[9];
    int K[9];
    int N[9];
};
__global__ __launch_bounds__(256) void wtrans_all(WJobs jobs) {
    int y = blockIdx.y;
    int K = jobs.K[y], N = jobs.N[y];
    int i = blockIdx.x * 256 + threadIdx.x;
    if (i >= K * N) return;
    int k = i / N, n = i % N;
    jobs.WT[y][(size_t)n * K + k] = f2bf(jobs.W[y][i]);
}

// ---------------- CSR mean-aggregate (bf16, 16B loads, sub-edge parallel) ----------------
template <int D>
__global__ __launch_bounds__(256) void aggregate_kernel(const u16* __restrict__ feat,
                                                        const int* __restrict__ csr_src,
                                                        const int* __restrict__ rowptr,
                                                        u16* __restrict__ out) {
    int node = blockIdx.x * 4 + (threadIdx.x >> 6);
    if (node >= NN) return;
    int lane = threadIdx.x & 63;
    int beg = rowptr[node], end = rowptr[node + 1];
    int cnt = end - beg;
    float inv = 1.0f / (float)(cnt > 0 ? cnt : 1);

    constexpr int NSUB = (D == 256) ? 2 : 4;
    constexpr int LPG = 64 / NSUB;
    int sub = lane / LPG;
    int c8 = lane % LPG;

    float a[8] = {0.f, 0.f, 0.f, 0.f, 0.f, 0.f, 0.f, 0.f};
    for (int e = beg + sub; e < end; e += NSUB) {
        int s = csr_src[e];
        bf16x8 u = *(const bf16x8*)(feat + (size_t)s * D + c8 * 8);
#pragma unroll
        for (int j = 0; j < 8; j++) a[j] += bf2f((u16)u[j]);
    }
#pragma unroll
    for (int j = 0; j < 8; j++) {
        if (NSUB == 4) a[j] += __shfl_xor(a[j], 16);
        a[j] += __shfl_xor(a[j], 32);
    }
    if (sub == 0) {
        bf16x8 o;
#pragma unroll
        for (int j = 0; j < 8; j++) o[j] = (short)f2bf(a[j] * inv);
        *(bf16x8*)(out + (size_t)node * D + c8 * 8) = o;
    }
}

// ---------------- gemm_v5: B pinned in VGPRs (asm), batched A, dual acc chains ----------------
// Grid (NGX, NN/32): x = 64-col group (fastest -> same-row blocks adjacent), y = 32-row
// chunk. Block = 4 waves; wave w owns 16 cols. B slices for ALL phases loaded once and
// PINNED via asm volatile (hipcc otherwise sinks the loads back into the loop - seen
// twice: VGPR_Count 60/44 instead of ~150). Inner loop per phase: 16 batched A-loads
// (2 row-blocks) then MFMA into 2 chains per row-block.
// mfma_f32_16x16x32_bf16 (m89-verified): A/B frag idx=lane&15, k=(lane>>4)*8+j;
// C/D: col=lane&15, row=(lane>>4)*4+reg.
template <int NK>
__device__ __forceinline__ void load_pin_b(const u16* __restrict__ BT, int col, int lhi,
                                           bf16x8* b) {
    const u16* bp = BT + (size_t)col * (NK * 32) + lhi * 8;
#pragma unroll
    for (int i = 0; i < NK; i++) b[i] = *(const bf16x8*)(bp + i * 32);
#pragma unroll
    for (int i = 0; i < NK; i++) asm volatile("" : "+v"(b[i]));   // pin: no sinking/remat
}

template <int NK, int NRB>
__device__ __forceinline__ void phase_v5(const u16* __restrict__ A, const bf16x8* b,
                                         int rowBeg, int l15, int lhi, f32x4 acc[][2]) {
    constexpr int K = NK * 32;
    bf16x8 af[NRB][NK];
#pragma unroll
    for (int rb = 0; rb < NRB; rb++) {
        const u16* ap = A + (size_t)(rowBeg + rb * 16 + l15) * K + lhi * 8;
#pragma unroll
        for (int i = 0; i < NK; i++) af[rb][i] = *(const bf16x8*)(ap + i * 32);
    }
#pragma unroll
    for (int rb = 0; rb < NRB; rb++)
#pragma unroll
        for (int i = 0; i < NK; i++)
            acc[rb][i & 1] = __builtin_amdgcn_mfma_f32_16x16x32_bf16(af[rb][i], b[i],
                                                                     acc[rb][i & 1], 0, 0, 0);
}

template <int NK0, int NK1, int NK2, int RELU01, int SPLIT, int OUT_F32>
__global__ __launch_bounds__(256) void gemm_v5(const u16* __restrict__ A0,
                                               const u16* __restrict__ B0T,
                                               const u16* __restrict__ A1,
                                               const u16* __restrict__ B1T,
                                               const u16* __restrict__ A2,
                                               const u16* __restrict__ B2T,
                                               const float* __restrict__ bias,
                                               const float* __restrict__ bias2,
                                               void* __restrict__ Cout,
                                               void* __restrict__ Cout2,
                                               int NOUT) {
    constexpr int NRB = 2;   // 32 rows per block
    int t = threadIdx.x;
    int w = t >> 6, l = t & 63;
    int l15 = l & 15, lhi = l >> 4;
    int col = (blockIdx.x * 4 + w) * 16 + l15;
    int rowBeg = blockIdx.y * (NRB * 16);

    f32x4 acc[NRB][2];
#pragma unroll
    for (int rb = 0; rb < NRB; rb++) {
        acc[rb][0] = f32x4{0.f, 0.f, 0.f, 0.f};
        acc[rb][1] = f32x4{0.f, 0.f, 0.f, 0.f};
    }

    float brelu = RELU01 ? bias[col] : 0.f;
    float badd;
    if constexpr (SPLIT)        badd = (col < 64) ? bias[col] : bias2[col - 64];
    else if constexpr (NK2 > 0) badd = bias2[col];
    else if constexpr (RELU01)  badd = 0.f;
    else                        badd = bias[col];

    bf16x8 b0[NK0], b1[NK1];
    load_pin_b<NK0>(B0T, col, lhi, b0);
    load_pin_b<NK1>(B1T, col, lhi, b1);
    bf16x8 b2[NK2 > 0 ? NK2 : 1];
    if constexpr (NK2 > 0) load_pin_b<NK2>(B2T, col, lhi, b2);

    phase_v5<NK0, NRB>(A0, b0, rowBeg, l15, lhi, acc);
    phase_v5<NK1, NRB>(A1, b1, rowBeg, l15, lhi, acc);

    if constexpr (RELU01) {
#pragma unroll
        for (int rb = 0; rb < NRB; rb++) {
#pragma unroll
            for (int r = 0; r < 4; r++) {
                acc[rb][0][r] = fmaxf(acc[rb][0][r] + acc[rb][1][r] + brelu, 0.f);
                acc[rb][1][r] = 0.f;
            }
        }
    }

    if constexpr (NK2 > 0) phase_v5<NK2, NRB>(A2, b2, rowBeg, l15, lhi, acc);

#pragma unroll
    for (int rb = 0; rb < NRB; rb++) {
#pragma unroll
        for (int reg = 0; reg < 4; reg++) {
            int r = rowBeg + rb * 16 + lhi * 4 + reg;
            float v = acc[rb][0][reg] + acc[rb][1][reg] + badd;
            if constexpr (SPLIT) {
                if (col < 64) ((float*)Cout)[(size_t)r * 64 + col] = v;
                else          ((float*)Cout2)[(size_t)r * 64 + (col - 64)] = v;
            } else if constexpr (OUT_F32) {
                ((float*)Cout)[(size_t)r * NOUT + col] = v;
            } else {
                ((u16*)Cout)[(size_t)r * NOUT + col] = f2bf(v);
            }
        }
    }
}

extern "C" void kernel_launch(void* const* d_in, const int* in_sizes, int n_in,
                              void* d_out, int out_size, void* d_ws, size_t ws_size,
                              hipStream_t stream) {
    const float* x    = (const float*)d_in[0];
    const void*  edges = d_in[1];
    const float* W1l  = (const float*)d_in[2];
    const float* b1   = (const float*)d_in[3];
    const float* W1r  = (const float*)d_in[4];
    const float* W2l  = (const float*)d_in[5];
    const float* b2   = (const float*)d_in[6];
    const float* W2r  = (const float*)d_in[7];
    const float* Wres = (const float*)d_in[8];
    const float* bres = (const float*)d_in[9];
    const float* Wmul = (const float*)d_in[10];
    const float* bmu  = (const float*)d_in[11];
    const float* Wmur = (const float*)d_in[12];
    const float* Wlsl = (const float*)d_in[13];
    const float* bls  = (const float*)d_in[14];
    const float* Wlsr = (const float*)d_in[15];
    float* out = (float*)d_out;

    char* ws = (char*)d_ws;
    size_t off = 0;
    int* flag    = (int*)(ws + off); off += 256;
    int* src     = (int*)(ws + off); off += (size_t)NE * 4;
    int* dst     = (int*)(ws + off); off += (size_t)NE * 4;
    int* csr_src = (int*)(ws + off); off += (size_t)NE * 4;
    int* deg     = (int*)(ws + off); off += (size_t)NN * 4;
    int* rowptr  = (int*)(ws + off); off += (size_t)(NN + 8) * 4;
    int* cursor  = (int*)(ws + off); off += (size_t)NN * 4;
    int* incl    = (int*)(ws + off); off += (size_t)NN * 4;
    int* bsum    = (int*)(ws + off); off += 256 * 4;
    int* boff    = (int*)(ws + off); off += 256 * 4;
    off = (off + 255) & ~(size_t)255;
    u16* xb    = (u16*)(ws + off); off += (size_t)NN * 128 * 2;
    u16* agg1b = (u16*)(ws + off); off += (size_t)NN * 128 * 2;
    u16* h1b   = (u16*)(ws + off); off += (size_t)NN * 256 * 2;
    u16* h2b   = (u16*)(ws + off); off += (size_t)NN * 256 * 2;
    u16* aggb  = (u16*)(ws + off); off += (size_t)NN * 256 * 2;   // agg2, then agg3
    u16* W1lT  = (u16*)(ws + off); off += 128 * 256 * 2;
    u16* W1rT  = (u16*)(ws + off); off += 128 * 256 * 2;
    u16* W2lT  = (u16*)(ws + off); off += 256 * 256 * 2;
    u16* W2rT  = (u16*)(ws + off); off += 256 * 256 * 2;
    u16* WresT = (u16*)(ws + off); off += 128 * 256 * 2;
    u16* WcatL = (u16*)(ws + off); off += 128 * 256 * 2;   // [Wmul | Wlsl]^T : [128][256]
    u16* WcatR = (u16*)(ws + off); off += 128 * 256 * 2;   // [Wmur | Wlsr]^T

    hipMemsetAsync(flag, 0, 4, stream);
    hipMemsetAsync(deg, 0, (size_t)NN * 4, stream);
    hipMemsetAsync(cursor, 0, (size_t)NN * 4, stream);

    const int SB = (NN + 255) / 256;   // 79

    detect_kernel<<<64, 256, 0, stream>>>(edges, flag);
    convert_kernel<<<NE / 256, 256, 0, stream>>>(edges, flag, src, dst, deg);
    scan1_kernel<<<SB, 256, 0, stream>>>(deg, incl, bsum);
    scan2_kernel<<<1, 256, 0, stream>>>(bsum, boff);
    scan3_kernel<<<SB, 256, 0, stream>>>(deg, incl, boff, rowptr);
    fill_kernel<<<NE / 256, 256, 0, stream>>>(src, dst, rowptr, cursor, csr_src);

    cast_kernel<<<(NN * 128 / 4 + 255) / 256, 256, 0, stream>>>(x, xb, NN * 128 / 4);

    WJobs jobs;
    jobs.W[0] = W1l;  jobs.WT[0] = W1lT;            jobs.K[0] = 128; jobs.N[0] = 256;
    jobs.W[1] = W1r;  jobs.WT[1] = W1rT;            jobs.K[1] = 128; jobs.N[1] = 256;
    jobs.W[2] = W2l;  jobs.WT[2] = W2lT;            jobs.K[2] = 256; jobs.N[2] = 256;
    jobs.W[3] = W2r;  jobs.WT[3] = W2rT;            jobs.K[3] = 256; jobs.N[3] = 256;
    jobs.W[4] = Wres; jobs.WT[4] = WresT;           jobs.K[4] = 128; jobs.N[4] = 256;
    jobs.W[5] = Wmul; jobs.WT[5] = WcatL;           jobs.K[5] = 256; jobs.N[5] = 64;
    jobs.W[6] = Wlsl; jobs.WT[6] = WcatL + 64*256;  jobs.K[6] = 256; jobs.N[6] = 64;
    jobs.W[7] = Wmur; jobs.WT[7] = WcatR;           jobs.K[7] = 256; jobs.N[7] = 64;
    jobs.W[8] = Wlsr; jobs.WT[8] = WcatR + 64*256;  jobs.K[8] = 256; jobs.N[8] = 64;
    wtrans_all<<<dim3(256, 9), 256, 0, stream>>>(jobs);

    const int RC = NN / 32;   // 625 row-chunks

    // layer 1: h1 = relu(mean(x)@W1l + x@W1r + b1)
    aggregate_kernel<128><<<NN / 4, 256, 0, stream>>>(xb, csr_src, rowptr, agg1b);
    gemm_v5<4, 4, 0, 1, 0, 0><<<dim3(4, RC), 256, 0, stream>>>(
        agg1b, W1lT, xb, W1rT, nullptr, nullptr, b1, nullptr, h1b, nullptr, 256);

    // layer 2 (fused residual): h2 = relu(mean(h1)@W2l + h1@W2r + b2) + x@Wres + bres
    aggregate_kernel<256><<<NN / 4, 256, 0, stream>>>(h1b, csr_src, rowptr, aggb);
    gemm_v5<8, 8, 4, 1, 0, 0><<<dim3(4, RC), 256, 0, stream>>>(
        aggb, W2lT, h1b, W2rT, xb, WresT, b2, bres, h2b, nullptr, 256);

    // layer 3 (fused mu+logstd): [mu|logstd] = mean(h2)@[Wmul|Wlsl] + h2@[Wmur|Wlsr] + [bmu|bls]
    aggregate_kernel<256><<<NN / 4, 256, 0, stream>>>(h2b, csr_src, rowptr, aggb);
    gemm_v5<8, 8, 0, 0, 1, 1><<<dim3(2, RC), 256, 0, stream>>>(
        aggb, WcatL, h2b, WcatR, nullptr, nullptr, bmu, bls, out, out + (size_t)NN * 64, 128);
}

// Round 11
// 196.517 us; speedup vs baseline: 1.3426x; 1.3426x over previous
//
#include <hip/hip_runtime.h>
#include <cstddef>

#define NN 20000
#define NE 320000

typedef short bf16x8 __attribute__((ext_vector_type(8)));
typedef float f32x4 __attribute__((ext_vector_type(4)));
typedef unsigned short u16;

__device__ __forceinline__ float bf2f(u16 u) {
    unsigned x = ((unsigned)u) << 16;
    return __builtin_bit_cast(float, x);
}
__device__ __forceinline__ u16 f2bf(float f) {
    unsigned x = __builtin_bit_cast(unsigned, f);
    x = (x + 0x7fff + ((x >> 16) & 1)) >> 16;   // round-to-nearest-even
    return (u16)x;
}

// ---------------- edge-index layout detection (low-contention) ----------------
__global__ __launch_bounds__(256) void detect_kernel(const void* __restrict__ edges, int* flag) {
    __shared__ int bad;
    if (threadIdx.x == 0) bad = 0;
    __syncthreads();
    int any = 0;
    for (int i = blockIdx.x * 256 + threadIdx.x; i < NE; i += 64 * 256) {
        long long v = ((const long long*)edges)[i];
        if (v < 0 || v >= NN) any = 1;
    }
    if (any) bad = 1;               // benign LDS race: all write 1
    __syncthreads();
    if (threadIdx.x == 0 && bad) atomicOr(flag, 1);
}

__global__ __launch_bounds__(256) void convert_kernel(const void* __restrict__ edges,
                                                      const int* __restrict__ flag,
                                                      int* __restrict__ src, int* __restrict__ dst,
                                                      int* __restrict__ deg) {
    int i = blockIdx.x * blockDim.x + threadIdx.x;
    if (i >= NE) return;
    int s, d;
    if (*flag) {
        s = ((const int*)edges)[i];
        d = ((const int*)edges)[NE + i];
    } else {
        s = (int)((const long long*)edges)[i];
        d = (int)((const long long*)edges)[NE + i];
    }
    src[i] = s;
    dst[i] = d;
    atomicAdd(&deg[d], 1);
}

// ---------------- parallel exclusive scan (3 phases) ----------------
__global__ __launch_bounds__(256) void scan1_kernel(const int* __restrict__ deg,
                                                    int* __restrict__ incl, int* __restrict__ bsum) {
    __shared__ int buf[256];
    int t = threadIdx.x, i = blockIdx.x * 256 + t;
    int v = (i < NN) ? deg[i] : 0;
    buf[t] = v;
    __syncthreads();
    for (int off = 1; off < 256; off <<= 1) {
        int u = (t >= off) ? buf[t - off] : 0;
        __syncthreads();
        buf[t] += u;
        __syncthreads();
    }
    if (i < NN) incl[i] = buf[t];
    if (t == 255) bsum[blockIdx.x] = buf[255];
}

__global__ __launch_bounds__(256) void scan2_kernel(const int* __restrict__ bsum,
                                                    int* __restrict__ boff) {
    __shared__ int buf[256];
    const int nb = (NN + 255) / 256;   // 79
    int t = threadIdx.x;
    int v = (t < nb) ? bsum[t] : 0;
    buf[t] = v;
    __syncthreads();
    for (int off = 1; off < 256; off <<= 1) {
        int u = (t >= off) ? buf[t - off] : 0;
        __syncthreads();
        buf[t] += u;
        __syncthreads();
    }
    if (t < nb) boff[t] = buf[t] - v;   // exclusive
}

__global__ __launch_bounds__(256) void scan3_kernel(const int* __restrict__ deg,
                                                    const int* __restrict__ incl,
                                                    const int* __restrict__ boff,
                                                    int* __restrict__ rowptr) {
    int i = blockIdx.x * 256 + threadIdx.x;
    if (i < NN) rowptr[i] = boff[i >> 8] + incl[i] - deg[i];
    if (i == NN) rowptr[NN] = NE;
}

// ---------------- CSR fill ----------------
__global__ __launch_bounds__(256) void fill_kernel(const int* __restrict__ src,
                                                   const int* __restrict__ dst,
                                                   const int* __restrict__ rowptr,
                                                   int* __restrict__ cursor,
                                                   int* __restrict__ csr_src) {
    int i = blockIdx.x * blockDim.x + threadIdx.x;
    if (i >= NE) return;
    int d = dst[i];
    int p = atomicAdd(&cursor[d], 1);
    csr_src[rowptr[d] + p] = src[i];
}

// ---------------- fp32 -> bf16 cast ----------------
__global__ __launch_bounds__(256) void cast_kernel(const float* __restrict__ in,
                                                   u16* __restrict__ out, int n4) {
    int i = blockIdx.x * 256 + threadIdx.x;
    if (i >= n4) return;
    float4 v = *(const float4*)(in + (size_t)i * 4);
    ushort4 o;
    o.x = f2bf(v.x); o.y = f2bf(v.y); o.z = f2bf(v.z); o.w = f2bf(v.w);
    *(ushort4*)(out + (size_t)i * 4) = o;
}

// ---------------- fused weight transpose+cast: 9 jobs in one dispatch ----------------
struct WJobs {
    const float* W[9];
    u16* WT[9];
    int K[9];
    int N[9];
};
__global__ __launch_bounds__(256) void wtrans_all(WJobs jobs) {
    int y = blockIdx.y;
    int K = jobs.K[y], N = jobs.N[y];
    int i = blockIdx.x * 256 + threadIdx.x;
    if (i >= K * N) return;
    int k = i / N, n = i % N;
    jobs.WT[y][(size_t)n * K + k] = f2bf(jobs.W[y][i]);
}

// ---------------- CSR mean-aggregate (bf16, 16B loads, sub-edge parallel) ----------------
template <int D>
__global__ __launch_bounds__(256) void aggregate_kernel(const u16* __restrict__ feat,
                                                        const int* __restrict__ csr_src,
                                                        const int* __restrict__ rowptr,
                                                        u16* __restrict__ out) {
    int node = blockIdx.x * 4 + (threadIdx.x >> 6);
    if (node >= NN) return;
    int lane = threadIdx.x & 63;
    int beg = rowptr[node], end = rowptr[node + 1];
    int cnt = end - beg;
    float inv = 1.0f / (float)(cnt > 0 ? cnt : 1);

    constexpr int NSUB = (D == 256) ? 2 : 4;
    constexpr int LPG = 64 / NSUB;
    int sub = lane / LPG;
    int c8 = lane % LPG;

    float a[8] = {0.f, 0.f, 0.f, 0.f, 0.f, 0.f, 0.f, 0.f};
    for (int e = beg + sub; e < end; e += NSUB) {
        int s = csr_src[e];
        bf16x8 u = *(const bf16x8*)(feat + (size_t)s * D + c8 * 8);
#pragma unroll
        for (int j = 0; j < 8; j++) a[j] += bf2f((u16)u[j]);
    }
#pragma unroll
    for (int j = 0; j < 8; j++) {
        if (NSUB == 4) a[j] += __shfl_xor(a[j], 16);
        a[j] += __shfl_xor(a[j], 32);
    }
    if (sub == 0) {
        bf16x8 o;
#pragma unroll
        for (int j = 0; j < 8; j++) o[j] = (short)f2bf(a[j] * inv);
        *(bf16x8*)(out + (size_t)node * D + c8 * 8) = o;
    }
}

// ---------------- gemm_lds: canonical LDS-staged double-buffered MFMA GEMM ----------------
// Block: 64 rows x NCOL (NCOL = NWAVES*64). Wave w owns 64 rows x 64 cols (4x4 frags).
// K-step = 32. Per step per wave: 4+4 ds_read_b128 -> 16 MFMAs (2:1 vs 1:1 before).
// Double-buffered LDS; next step's tiles prefetched to regs between the two barriers
// so global latency hides under compute. Phases: acc += A0@B0 + A1@B1 [relu+bias]
// [+= A2@B2]; epilogue adds badd. LDS layouts (lane-linear, bank-even, no swizzle):
// A [64 rows][32 k] row-major; B [NCOL n][32 k] n-major (BT input is [N][K]).
// mfma_f32_16x16x32_bf16 (m89-verified): A/B frag idx=lane&15, k=(lane>>4)*8+j;
// C/D: col=lane&15, row=(lane>>4)*4+reg.
template <int KS0, int KS1, int KS2, int RELU01, int SPLIT, int OUT_F32, int NWAVES>
__global__ __launch_bounds__(NWAVES * 64) void gemm_lds(
    const u16* __restrict__ A0, const u16* __restrict__ B0T,
    const u16* __restrict__ A1, const u16* __restrict__ B1T,
    const u16* __restrict__ A2, const u16* __restrict__ B2T,
    const float* __restrict__ bias, const float* __restrict__ bias2,
    void* __restrict__ Cout, void* __restrict__ Cout2, int M) {
    constexpr int NT = NWAVES * 64;               // threads
    constexpr int NCOL = NWAVES * 64;             // output cols
    constexpr int AI = 4096 / (NT * 16);          // A staging loads/thread (64*32*2B)
    constexpr int BI = (NCOL * 64) / (NT * 16);   // B staging loads/thread
    constexpr int TOT = KS0 + KS1 + KS2;
    constexpr int pS1 = KS0, pS2 = KS0 + KS1;
    constexpr int BOFF = 64 * 32;                 // u16 offset of B region in a buffer
    constexpr int BUFSZ = BOFF + NCOL * 32;

    __shared__ __align__(16) u16 smem[2][BUFSZ];

    const int t = threadIdx.x;
    const int w = t >> 6, l = t & 63;
    const int l15 = l & 15, lhi = l >> 4;
    const int rowBase = blockIdx.x * 64;
    const int wc = w * 64;
    const int srow = t >> 2, skk = t & 3;         // staging coords

    f32x4 acc[4][4];
#pragma unroll
    for (int r = 0; r < 4; r++)
#pragma unroll
        for (int n = 0; n < 4; n++) acc[r][n] = f32x4{0.f, 0.f, 0.f, 0.f};

    bf16x8 ar[AI], br[BI];

    auto gload = [&](const u16* __restrict__ A, const u16* __restrict__ BT, int K, int ko) {
#pragma unroll
        for (int i = 0; i < AI; i++) {
            int row = rowBase + i * (NT / 4) + srow;
            row = row < M ? row : M - 1;
            ar[i] = *(const bf16x8*)(A + (size_t)row * K + ko + skk * 8);
        }
#pragma unroll
        for (int i = 0; i < BI; i++) {
            int n = i * (NT / 4) + srow;
            br[i] = *(const bf16x8*)(BT + (size_t)n * K + ko + skk * 8);
        }
    };
    auto swrite = [&](int buf) {
        u16* base = smem[buf];
#pragma unroll
        for (int i = 0; i < AI; i++)
            *(bf16x8*)(base + (size_t)(i * NT + t) * 8) = ar[i];
#pragma unroll
        for (int i = 0; i < BI; i++)
            *(bf16x8*)(base + BOFF + (size_t)(i * NT + t) * 8) = br[i];
    };

    gload(A0, B0T, KS0 * 32, 0);   // prologue: stage step 0 into regs
    int cur = 0;

#pragma unroll 1
    for (int step = 0; step < TOT; step++) {
        __syncthreads();           // buf[cur] consumers (prev iter) done
        swrite(cur);
        int ns = step + 1;
        if (ns < TOT) {            // prefetch next step (in flight across compute)
            if (KS2 > 0 && ns >= pS2)  gload(A2, B2T, KS2 * 32, (ns - pS2) * 32);
            else if (ns >= pS1)        gload(A1, B1T, KS1 * 32, (ns - pS1) * 32);
            else                       gload(A0, B0T, KS0 * 32, ns * 32);
        }
        __syncthreads();           // buf[cur] visible to all
        const u16* sb = smem[cur];
        bf16x8 af[4], bf[4];
#pragma unroll
        for (int r = 0; r < 4; r++)
            af[r] = *(const bf16x8*)(sb + (r * 16 + l15) * 32 + lhi * 8);
#pragma unroll
        for (int n = 0; n < 4; n++)
            bf[n] = *(const bf16x8*)(sb + BOFF + (wc + n * 16 + l15) * 32 + lhi * 8);
#pragma unroll
        for (int r = 0; r < 4; r++)
#pragma unroll
            for (int n = 0; n < 4; n++)
                acc[r][n] = __builtin_amdgcn_mfma_f32_16x16x32_bf16(af[r], bf[n], acc[r][n], 0, 0, 0);
        if (RELU01 && step == pS2 - 1) {
#pragma unroll
            for (int n = 0; n < 4; n++) {
                float b = bias[wc + n * 16 + l15];
#pragma unroll
                for (int r = 0; r < 4; r++)
#pragma unroll
                    for (int j = 0; j < 4; j++)
                        acc[r][n][j] = fmaxf(acc[r][n][j] + b, 0.f);
            }
        }
        cur ^= 1;
    }

#pragma unroll
    for (int n = 0; n < 4; n++) {
        int col = wc + n * 16 + l15;
        float badd;
        if constexpr (SPLIT)        badd = (col < 64) ? bias[col] : bias2[col - 64];
        else if constexpr (KS2 > 0) badd = bias2[col];
        else if constexpr (RELU01)  badd = 0.f;
        else                        badd = bias[col];
#pragma unroll
        for (int r = 0; r < 4; r++) {
#pragma unroll
            for (int j = 0; j < 4; j++) {
                int row = rowBase + r * 16 + lhi * 4 + j;
                if (row >= M) continue;
                float v = acc[r][n][j] + badd;
                if constexpr (SPLIT) {
                    if (col < 64) ((float*)Cout)[(size_t)row * 64 + col] = v;
                    else          ((float*)Cout2)[(size_t)row * 64 + (col - 64)] = v;
                } else if constexpr (OUT_F32) {
                    ((float*)Cout)[(size_t)row * NCOL + col] = v;
                } else {
                    ((u16*)Cout)[(size_t)row * NCOL + col] = f2bf(v);
                }
            }
        }
    }
}

extern "C" void kernel_launch(void* const* d_in, const int* in_sizes, int n_in,
                              void* d_out, int out_size, void* d_ws, size_t ws_size,
                              hipStream_t stream) {
    const float* x    = (const float*)d_in[0];
    const void*  edges = d_in[1];
    const float* W1l  = (const float*)d_in[2];
    const float* b1   = (const float*)d_in[3];
    const float* W1r  = (const float*)d_in[4];
    const float* W2l  = (const float*)d_in[5];
    const float* b2   = (const float*)d_in[6];
    const float* W2r  = (const float*)d_in[7];
    const float* Wres = (const float*)d_in[8];
    const float* bres = (const float*)d_in[9];
    const float* Wmul = (const float*)d_in[10];
    const float* bmu  = (const float*)d_in[11];
    const float* Wmur = (const float*)d_in[12];
    const float* Wlsl = (const float*)d_in[13];
    const float* bls  = (const float*)d_in[14];
    const float* Wlsr = (const float*)d_in[15];
    float* out = (float*)d_out;

    char* ws = (char*)d_ws;
    size_t off = 0;
    int* flag    = (int*)(ws + off); off += 256;
    int* src     = (int*)(ws + off); off += (size_t)NE * 4;
    int* dst     = (int*)(ws + off); off += (size_t)NE * 4;
    int* csr_src = (int*)(ws + off); off += (size_t)NE * 4;
    int* deg     = (int*)(ws + off); off += (size_t)NN * 4;
    int* rowptr  = (int*)(ws + off); off += (size_t)(NN + 8) * 4;
    int* cursor  = (int*)(ws + off); off += (size_t)NN * 4;
    int* incl    = (int*)(ws + off); off += (size_t)NN * 4;
    int* bsum    = (int*)(ws + off); off += 256 * 4;
    int* boff    = (int*)(ws + off); off += 256 * 4;
    off = (off + 255) & ~(size_t)255;
    u16* xb    = (u16*)(ws + off); off += (size_t)NN * 128 * 2;
    u16* agg1b = (u16*)(ws + off); off += (size_t)NN * 128 * 2;
    u16* h1b   = (u16*)(ws + off); off += (size_t)NN * 256 * 2;
    u16* h2b   = (u16*)(ws + off); off += (size_t)NN * 256 * 2;
    u16* aggb  = (u16*)(ws + off); off += (size_t)NN * 256 * 2;   // agg2, then agg3
    u16* W1lT  = (u16*)(ws + off); off += 128 * 256 * 2;
    u16* W1rT  = (u16*)(ws + off); off += 128 * 256 * 2;
    u16* W2lT  = (u16*)(ws + off); off += 256 * 256 * 2;
    u16* W2rT  = (u16*)(ws + off); off += 256 * 256 * 2;
    u16* WresT = (u16*)(ws + off); off += 128 * 256 * 2;
    u16* WcatL = (u16*)(ws + off); off += 128 * 256 * 2;   // [Wmul | Wlsl]^T : [128][256]
    u16* WcatR = (u16*)(ws + off); off += 128 * 256 * 2;   // [Wmur | Wlsr]^T

    hipMemsetAsync(flag, 0, 4, stream);
    hipMemsetAsync(deg, 0, (size_t)NN * 4, stream);
    hipMemsetAsync(cursor, 0, (size_t)NN * 4, stream);

    const int SB = (NN + 255) / 256;   // 79

    detect_kernel<<<64, 256, 0, stream>>>(edges, flag);
    convert_kernel<<<NE / 256, 256, 0, stream>>>(edges, flag, src, dst, deg);
    scan1_kernel<<<SB, 256, 0, stream>>>(deg, incl, bsum);
    scan2_kernel<<<1, 256, 0, stream>>>(bsum, boff);
    scan3_kernel<<<SB, 256, 0, stream>>>(deg, incl, boff, rowptr);
    fill_kernel<<<NE / 256, 256, 0, stream>>>(src, dst, rowptr, cursor, csr_src);

    cast_kernel<<<(NN * 128 / 4 + 255) / 256, 256, 0, stream>>>(x, xb, NN * 128 / 4);

    WJobs jobs;
    jobs.W[0] = W1l;  jobs.WT[0] = W1lT;            jobs.K[0] = 128; jobs.N[0] = 256;
    jobs.W[1] = W1r;  jobs.WT[1] = W1rT;            jobs.K[1] = 128; jobs.N[1] = 256;
    jobs.W[2] = W2l;  jobs.WT[2] = W2lT;            jobs.K[2] = 256; jobs.N[2] = 256;
    jobs.W[3] = W2r;  jobs.WT[3] = W2rT;            jobs.K[3] = 256; jobs.N[3] = 256;
    jobs.W[4] = Wres; jobs.WT[4] = WresT;           jobs.K[4] = 128; jobs.N[4] = 256;
    jobs.W[5] = Wmul; jobs.WT[5] = WcatL;           jobs.K[5] = 256; jobs.N[5] = 64;
    jobs.W[6] = Wlsl; jobs.WT[6] = WcatL + 64*256;  jobs.K[6] = 256; jobs.N[6] = 64;
    jobs.W[7] = Wmur; jobs.WT[7] = WcatR;           jobs.K[7] = 256; jobs.N[7] = 64;
    jobs.W[8] = Wlsr; jobs.WT[8] = WcatR + 64*256;  jobs.K[8] = 256; jobs.N[8] = 64;
    wtrans_all<<<dim3(256, 9), 256, 0, stream>>>(jobs);

    const int GB = (NN + 63) / 64;   // 313

    // layer 1: h1 = relu(mean(x)@W1l + x@W1r + b1)
    aggregate_kernel<128><<<NN / 4, 256, 0, stream>>>(xb, csr_src, rowptr, agg1b);
    gemm_lds<4, 4, 0, 1, 0, 0, 4><<<GB, 256, 0, stream>>>(
        agg1b, W1lT, xb, W1rT, nullptr, nullptr, b1, nullptr, h1b, nullptr, NN);

    // layer 2 (fused residual): h2 = relu(mean(h1)@W2l + h1@W2r + b2) + x@Wres + bres
    aggregate_kernel<256><<<NN / 4, 256, 0, stream>>>(h1b, csr_src, rowptr, aggb);
    gemm_lds<8, 8, 4, 1, 0, 0, 4><<<GB, 256, 0, stream>>>(
        aggb, W2lT, h1b, W2rT, xb, WresT, b2, bres, h2b, nullptr, NN);

    // layer 3 (fused mu+logstd): [mu|logstd] = mean(h2)@[Wmul|Wlsl] + h2@[Wmur|Wlsr] + [bmu|bls]
    aggregate_kernel<256><<<NN / 4, 256, 0, stream>>>(h2b, csr_src, rowptr, aggb);
    gemm_lds<8, 8, 0, 0, 1, 1, 2><<<GB, 128, 0, stream>>>(
        aggb, WcatL, h2b, WcatR, nullptr, nullptr, bmu, bls, out, out + (size_t)NN * 64, NN);
}

// Round 12
// 184.064 us; speedup vs baseline: 1.4335x; 1.0677x over previous
//
#include <hip/hip_runtime.h>
#include <cstddef>

#define NN 20000
#define NE 320000

typedef short bf16x8 __attribute__((ext_vector_type(8)));
typedef float f32x4 __attribute__((ext_vector_type(4)));
typedef unsigned short u16;

__device__ __forceinline__ float bf2f(u16 u) {
    unsigned x = ((unsigned)u) << 16;
    return __builtin_bit_cast(float, x);
}
__device__ __forceinline__ u16 f2bf(float f) {
    unsigned x = __builtin_bit_cast(unsigned, f);
    x = (x + 0x7fff + ((x >> 16) & 1)) >> 16;   // round-to-nearest-even
    return (u16)x;
}

// ---------------- edge-index layout detection (low-contention) ----------------
__global__ __launch_bounds__(256) void detect_kernel(const void* __restrict__ edges, int* flag) {
    __shared__ int bad;
    if (threadIdx.x == 0) bad = 0;
    __syncthreads();
    int any = 0;
    for (int i = blockIdx.x * 256 + threadIdx.x; i < NE; i += 64 * 256) {
        long long v = ((const long long*)edges)[i];
        if (v < 0 || v >= NN) any = 1;
    }
    if (any) bad = 1;               // benign LDS race: all write 1
    __syncthreads();
    if (threadIdx.x == 0 && bad) atomicOr(flag, 1);
}

__global__ __launch_bounds__(256) void convert_kernel(const void* __restrict__ edges,
                                                      const int* __restrict__ flag,
                                                      int* __restrict__ src, int* __restrict__ dst,
                                                      int* __restrict__ deg) {
    int i = blockIdx.x * blockDim.x + threadIdx.x;
    if (i >= NE) return;
    int s, d;
    if (*flag) {
        s = ((const int*)edges)[i];
        d = ((const int*)edges)[NE + i];
    } else {
        s = (int)((const long long*)edges)[i];
        d = (int)((const long long*)edges)[NE + i];
    }
    src[i] = s;
    dst[i] = d;
    atomicAdd(&deg[d], 1);
}

// ---------------- parallel exclusive scan (3 phases) ----------------
__global__ __launch_bounds__(256) void scan1_kernel(const int* __restrict__ deg,
                                                    int* __restrict__ incl, int* __restrict__ bsum) {
    __shared__ int buf[256];
    int t = threadIdx.x, i = blockIdx.x * 256 + t;
    int v = (i < NN) ? deg[i] : 0;
    buf[t] = v;
    __syncthreads();
    for (int off = 1; off < 256; off <<= 1) {
        int u = (t >= off) ? buf[t - off] : 0;
        __syncthreads();
        buf[t] += u;
        __syncthreads();
    }
    if (i < NN) incl[i] = buf[t];
    if (t == 255) bsum[blockIdx.x] = buf[255];
}

__global__ __launch_bounds__(256) void scan2_kernel(const int* __restrict__ bsum,
                                                    int* __restrict__ boff) {
    __shared__ int buf[256];
    const int nb = (NN + 255) / 256;   // 79
    int t = threadIdx.x;
    int v = (t < nb) ? bsum[t] : 0;
    buf[t] = v;
    __syncthreads();
    for (int off = 1; off < 256; off <<= 1) {
        int u = (t >= off) ? buf[t - off] : 0;
        __syncthreads();
        buf[t] += u;
        __syncthreads();
    }
    if (t < nb) boff[t] = buf[t] - v;   // exclusive
}

__global__ __launch_bounds__(256) void scan3_kernel(const int* __restrict__ deg,
                                                    const int* __restrict__ incl,
                                                    const int* __restrict__ boff,
                                                    int* __restrict__ rowptr) {
    int i = blockIdx.x * 256 + threadIdx.x;
    if (i < NN) rowptr[i] = boff[i >> 8] + incl[i] - deg[i];
    if (i == NN) rowptr[NN] = NE;
}

// ---------------- CSR fill ----------------
__global__ __launch_bounds__(256) void fill_kernel(const int* __restrict__ src,
                                                   const int* __restrict__ dst,
                                                   const int* __restrict__ rowptr,
                                                   int* __restrict__ cursor,
                                                   int* __restrict__ csr_src) {
    int i = blockIdx.x * blockDim.x + threadIdx.x;
    if (i >= NE) return;
    int d = dst[i];
    int p = atomicAdd(&cursor[d], 1);
    csr_src[rowptr[d] + p] = src[i];
}

// ---------------- fp32 -> bf16 cast ----------------
__global__ __launch_bounds__(256) void cast_kernel(const float* __restrict__ in,
                                                   u16* __restrict__ out, int n4) {
    int i = blockIdx.x * 256 + threadIdx.x;
    if (i >= n4) return;
    float4 v = *(const float4*)(in + (size_t)i * 4);
    ushort4 o;
    o.x = f2bf(v.x); o.y = f2bf(v.y); o.z = f2bf(v.z); o.w = f2bf(v.w);
    *(ushort4*)(out + (size_t)i * 4) = o;
}

// ---------------- fused weight transpose+cast: 9 jobs in one dispatch ----------------
struct WJobs {
    const float* W[9];
    u16* WT[9];
    int K[9];
    int N[9];
};
__global__ __launch_bounds__(256) void wtrans_all(WJobs jobs) {
    int y = blockIdx.y;
    int K = jobs.K[y], N = jobs.N[y];
    int i = blockIdx.x * 256 + threadIdx.x;
    if (i >= K * N) return;
    int k = i / N, n = i % N;
    jobs.WT[y][(size_t)n * K + k] = f2bf(jobs.W[y][i]);
}

// ---------------- CSR mean-aggregate v2: 4x-unrolled MLP ----------------
// One wave per node. NSUB edge-groups; edge loop unrolled 4x so each wave keeps
// 4*NSUB independent row-gathers (plus batched index loads) in flight - attacks
// the two-level dependent-load chain (csr_src[e] -> feat row) that left only
// NSUB loads outstanding.
template <int D>
__global__ __launch_bounds__(256) void aggregate_kernel(const u16* __restrict__ feat,
                                                        const int* __restrict__ csr_src,
                                                        const int* __restrict__ rowptr,
                                                        u16* __restrict__ out) {
    int node = blockIdx.x * 4 + (threadIdx.x >> 6);
    if (node >= NN) return;
    int lane = threadIdx.x & 63;
    int beg = rowptr[node], end = rowptr[node + 1];
    int cnt = end - beg;
    float inv = 1.0f / (float)(cnt > 0 ? cnt : 1);

    constexpr int NSUB = (D == 256) ? 2 : 4;
    constexpr int LPG = 64 / NSUB;
    int sub = lane / LPG;
    int c8 = lane % LPG;
    const u16* fc = feat + c8 * 8;

    float a0[8] = {0.f,0.f,0.f,0.f,0.f,0.f,0.f,0.f};
    float a1[8] = {0.f,0.f,0.f,0.f,0.f,0.f,0.f,0.f};

    int e = beg + sub;
    // main: 4 edges in flight per group (4*NSUB per wave)
    for (; e + 3 * NSUB < end; e += 4 * NSUB) {
        int s0 = csr_src[e];
        int s1 = csr_src[e + NSUB];
        int s2 = csr_src[e + 2 * NSUB];
        int s3 = csr_src[e + 3 * NSUB];
        bf16x8 u0 = *(const bf16x8*)(fc + (size_t)s0 * D);
        bf16x8 u1 = *(const bf16x8*)(fc + (size_t)s1 * D);
        bf16x8 u2 = *(const bf16x8*)(fc + (size_t)s2 * D);
        bf16x8 u3 = *(const bf16x8*)(fc + (size_t)s3 * D);
#pragma unroll
        for (int j = 0; j < 8; j++) {
            a0[j] += bf2f((u16)u0[j]) + bf2f((u16)u2[j]);
            a1[j] += bf2f((u16)u1[j]) + bf2f((u16)u3[j]);
        }
    }
    for (; e < end; e += NSUB) {
        int s = csr_src[e];
        bf16x8 u = *(const bf16x8*)(fc + (size_t)s * D);
#pragma unroll
        for (int j = 0; j < 8; j++) a0[j] += bf2f((u16)u[j]);
    }
#pragma unroll
    for (int j = 0; j < 8; j++) {
        a0[j] += a1[j];
        if (NSUB == 4) a0[j] += __shfl_xor(a0[j], 16);
        a0[j] += __shfl_xor(a0[j], 32);
    }
    if (sub == 0) {
        bf16x8 o;
#pragma unroll
        for (int j = 0; j < 8; j++) o[j] = (short)f2bf(a0[j] * inv);
        *(bf16x8*)(out + (size_t)node * D + c8 * 8) = o;
    }
}

// ---------------- gemm_lds: canonical LDS-staged double-buffered MFMA GEMM ----------------
// Block: 64 rows x NCOL (NCOL = NWAVES*64). Wave w owns 64 rows x 64 cols (4x4 frags).
// K-step = 32. Per step per wave: 4+4 ds_read_b128 -> 16 MFMAs. Double-buffered LDS;
// next step's tiles reg-prefetched between the two barriers. Phases: acc += A0@B0 +
// A1@B1 [relu+bias] [+= A2@B2]; epilogue adds badd.
// mfma_f32_16x16x32_bf16 (m89-verified): A/B frag idx=lane&15, k=(lane>>4)*8+j;
// C/D: col=lane&15, row=(lane>>4)*4+reg.
template <int KS0, int KS1, int KS2, int RELU01, int SPLIT, int OUT_F32, int NWAVES>
__global__ __launch_bounds__(NWAVES * 64) void gemm_lds(
    const u16* __restrict__ A0, const u16* __restrict__ B0T,
    const u16* __restrict__ A1, const u16* __restrict__ B1T,
    const u16* __restrict__ A2, const u16* __restrict__ B2T,
    const float* __restrict__ bias, const float* __restrict__ bias2,
    void* __restrict__ Cout, void* __restrict__ Cout2, int M) {
    constexpr int NT = NWAVES * 64;               // threads
    constexpr int NCOL = NWAVES * 64;             // output cols
    constexpr int AI = 4096 / (NT * 16);          // A staging loads/thread (64*32*2B)
    constexpr int BI = (NCOL * 64) / (NT * 16);   // B staging loads/thread
    constexpr int TOT = KS0 + KS1 + KS2;
    constexpr int pS1 = KS0, pS2 = KS0 + KS1;
    constexpr int BOFF = 64 * 32;                 // u16 offset of B region in a buffer
    constexpr int BUFSZ = BOFF + NCOL * 32;

    __shared__ __align__(16) u16 smem[2][BUFSZ];

    const int t = threadIdx.x;
    const int w = t >> 6, l = t & 63;
    const int l15 = l & 15, lhi = l >> 4;
    const int rowBase = blockIdx.x * 64;
    const int wc = w * 64;
    const int srow = t >> 2, skk = t & 3;         // staging coords

    f32x4 acc[4][4];
#pragma unroll
    for (int r = 0; r < 4; r++)
#pragma unroll
        for (int n = 0; n < 4; n++) acc[r][n] = f32x4{0.f, 0.f, 0.f, 0.f};

    bf16x8 ar[AI], br[BI];

    auto gload = [&](const u16* __restrict__ A, const u16* __restrict__ BT, int K, int ko) {
#pragma unroll
        for (int i = 0; i < AI; i++) {
            int row = rowBase + i * (NT / 4) + srow;
            row = row < M ? row : M - 1;
            ar[i] = *(const bf16x8*)(A + (size_t)row * K + ko + skk * 8);
        }
#pragma unroll
        for (int i = 0; i < BI; i++) {
            int n = i * (NT / 4) + srow;
            br[i] = *(const bf16x8*)(BT + (size_t)n * K + ko + skk * 8);
        }
    };
    auto swrite = [&](int buf) {
        u16* base = smem[buf];
#pragma unroll
        for (int i = 0; i < AI; i++)
            *(bf16x8*)(base + (size_t)(i * NT + t) * 8) = ar[i];
#pragma unroll
        for (int i = 0; i < BI; i++)
            *(bf16x8*)(base + BOFF + (size_t)(i * NT + t) * 8) = br[i];
    };

    gload(A0, B0T, KS0 * 32, 0);   // prologue: stage step 0 into regs
    int cur = 0;

#pragma unroll 1
    for (int step = 0; step < TOT; step++) {
        __syncthreads();           // buf[cur] consumers (prev iter) done
        swrite(cur);
        int ns = step + 1;
        if (ns < TOT) {            // prefetch next step (in flight across compute)
            if (KS2 > 0 && ns >= pS2)  gload(A2, B2T, KS2 * 32, (ns - pS2) * 32);
            else if (ns >= pS1)        gload(A1, B1T, KS1 * 32, (ns - pS1) * 32);
            else                       gload(A0, B0T, KS0 * 32, ns * 32);
        }
        __syncthreads();           // buf[cur] visible to all
        const u16* sb = smem[cur];
        bf16x8 af[4], bf[4];
#pragma unroll
        for (int r = 0; r < 4; r++)
            af[r] = *(const bf16x8*)(sb + (r * 16 + l15) * 32 + lhi * 8);
#pragma unroll
        for (int n = 0; n < 4; n++)
            bf[n] = *(const bf16x8*)(sb + BOFF + (wc + n * 16 + l15) * 32 + lhi * 8);
#pragma unroll
        for (int r = 0; r < 4; r++)
#pragma unroll
            for (int n = 0; n < 4; n++)
                acc[r][n] = __builtin_amdgcn_mfma_f32_16x16x32_bf16(af[r], bf[n], acc[r][n], 0, 0, 0);
        if (RELU01 && step == pS2 - 1) {
#pragma unroll
            for (int n = 0; n < 4; n++) {
                float b = bias[wc + n * 16 + l15];
#pragma unroll
                for (int r = 0; r < 4; r++)
#pragma unroll
                    for (int j = 0; j < 4; j++)
                        acc[r][n][j] = fmaxf(acc[r][n][j] + b, 0.f);
            }
        }
        cur ^= 1;
    }

#pragma unroll
    for (int n = 0; n < 4; n++) {
        int col = wc + n * 16 + l15;
        float badd;
        if constexpr (SPLIT)        badd = (col < 64) ? bias[col] : bias2[col - 64];
        else if constexpr (KS2 > 0) badd = bias2[col];
        else if constexpr (RELU01)  badd = 0.f;
        else                        badd = bias[col];
#pragma unroll
        for (int r = 0; r < 4; r++) {
#pragma unroll
            for (int j = 0; j < 4; j++) {
                int row = rowBase + r * 16 + lhi * 4 + j;
                if (row >= M) continue;
                float v = acc[r][n][j] + badd;
                if constexpr (SPLIT) {
                    if (col < 64) ((float*)Cout)[(size_t)row * 64 + col] = v;
                    else          ((float*)Cout2)[(size_t)row * 64 + (col - 64)] = v;
                } else if constexpr (OUT_F32) {
                    ((float*)Cout)[(size_t)row * NCOL + col] = v;
                } else {
                    ((u16*)Cout)[(size_t)row * NCOL + col] = f2bf(v);
                }
            }
        }
    }
}

extern "C" void kernel_launch(void* const* d_in, const int* in_sizes, int n_in,
                              void* d_out, int out_size, void* d_ws, size_t ws_size,
                              hipStream_t stream) {
    const float* x    = (const float*)d_in[0];
    const void*  edges = d_in[1];
    const float* W1l  = (const float*)d_in[2];
    const float* b1   = (const float*)d_in[3];
    const float* W1r  = (const float*)d_in[4];
    const float* W2l  = (const float*)d_in[5];
    const float* b2   = (const float*)d_in[6];
    const float* W2r  = (const float*)d_in[7];
    const float* Wres = (const float*)d_in[8];
    const float* bres = (const float*)d_in[9];
    const float* Wmul = (const float*)d_in[10];
    const float* bmu  = (const float*)d_in[11];
    const float* Wmur = (const float*)d_in[12];
    const float* Wlsl = (const float*)d_in[13];
    const float* bls  = (const float*)d_in[14];
    const float* Wlsr = (const float*)d_in[15];
    float* out = (float*)d_out;

    char* ws = (char*)d_ws;
    size_t off = 0;
    int* flag    = (int*)(ws + off); off += 256;
    int* src     = (int*)(ws + off); off += (size_t)NE * 4;
    int* dst     = (int*)(ws + off); off += (size_t)NE * 4;
    int* csr_src = (int*)(ws + off); off += (size_t)NE * 4;
    int* deg     = (int*)(ws + off); off += (size_t)NN * 4;
    int* rowptr  = (int*)(ws + off); off += (size_t)(NN + 8) * 4;
    int* cursor  = (int*)(ws + off); off += (size_t)NN * 4;
    int* incl    = (int*)(ws + off); off += (size_t)NN * 4;
    int* bsum    = (int*)(ws + off); off += 256 * 4;
    int* boff    = (int*)(ws + off); off += 256 * 4;
    off = (off + 255) & ~(size_t)255;
    u16* xb    = (u16*)(ws + off); off += (size_t)NN * 128 * 2;
    u16* agg1b = (u16*)(ws + off); off += (size_t)NN * 128 * 2;
    u16* h1b   = (u16*)(ws + off); off += (size_t)NN * 256 * 2;
    u16* h2b   = (u16*)(ws + off); off += (size_t)NN * 256 * 2;
    u16* aggb  = (u16*)(ws + off); off += (size_t)NN * 256 * 2;   // agg2, then agg3
    u16* W1lT  = (u16*)(ws + off); off += 128 * 256 * 2;
    u16* W1rT  = (u16*)(ws + off); off += 128 * 256 * 2;
    u16* W2lT  = (u16*)(ws + off); off += 256 * 256 * 2;
    u16* W2rT  = (u16*)(ws + off); off += 256 * 256 * 2;
    u16* WresT = (u16*)(ws + off); off += 128 * 256 * 2;
    u16* WcatL = (u16*)(ws + off); off += 128 * 256 * 2;   // [Wmul | Wlsl]^T : [128][256]
    u16* WcatR = (u16*)(ws + off); off += 128 * 256 * 2;   // [Wmur | Wlsr]^T

    hipMemsetAsync(flag, 0, 4, stream);
    hipMemsetAsync(deg, 0, (size_t)NN * 4, stream);
    hipMemsetAsync(cursor, 0, (size_t)NN * 4, stream);

    const int SB = (NN + 255) / 256;   // 79

    detect_kernel<<<64, 256, 0, stream>>>(edges, flag);
    convert_kernel<<<NE / 256, 256, 0, stream>>>(edges, flag, src, dst, deg);
    scan1_kernel<<<SB, 256, 0, stream>>>(deg, incl, bsum);
    scan2_kernel<<<1, 256, 0, stream>>>(bsum, boff);
    scan3_kernel<<<SB, 256, 0, stream>>>(deg, incl, boff, rowptr);
    fill_kernel<<<NE / 256, 256, 0, stream>>>(src, dst, rowptr, cursor, csr_src);

    cast_kernel<<<(NN * 128 / 4 + 255) / 256, 256, 0, stream>>>(x, xb, NN * 128 / 4);

    WJobs jobs;
    jobs.W[0] = W1l;  jobs.WT[0] = W1lT;            jobs.K[0] = 128; jobs.N[0] = 256;
    jobs.W[1] = W1r;  jobs.WT[1] = W1rT;            jobs.K[1] = 128; jobs.N[1] = 256;
    jobs.W[2] = W2l;  jobs.WT[2] = W2lT;            jobs.K[2] = 256; jobs.N[2] = 256;
    jobs.W[3] = W2r;  jobs.WT[3] = W2rT;            jobs.K[3] = 256; jobs.N[3] = 256;
    jobs.W[4] = Wres; jobs.WT[4] = WresT;           jobs.K[4] = 128; jobs.N[4] = 256;
    jobs.W[5] = Wmul; jobs.WT[5] = WcatL;           jobs.K[5] = 256; jobs.N[5] = 64;
    jobs.W[6] = Wlsl; jobs.WT[6] = WcatL + 64*256;  jobs.K[6] = 256; jobs.N[6] = 64;
    jobs.W[7] = Wmur; jobs.WT[7] = WcatR;           jobs.K[7] = 256; jobs.N[7] = 64;
    jobs.W[8] = Wlsr; jobs.WT[8] = WcatR + 64*256;  jobs.K[8] = 256; jobs.N[8] = 64;
    wtrans_all<<<dim3(256, 9), 256, 0, stream>>>(jobs);

    const int GB = (NN + 63) / 64;   // 313

    // layer 1: h1 = relu(mean(x)@W1l + x@W1r + b1)
    aggregate_kernel<128><<<NN / 4, 256, 0, stream>>>(xb, csr_src, rowptr, agg1b);
    gemm_lds<4, 4, 0, 1, 0, 0, 4><<<GB, 256, 0, stream>>>(
        agg1b, W1lT, xb, W1rT, nullptr, nullptr, b1, nullptr, h1b, nullptr, NN);

    // layer 2 (fused residual): h2 = relu(mean(h1)@W2l + h1@W2r + b2) + x@Wres + bres
    aggregate_kernel<256><<<NN / 4, 256, 0, stream>>>(h1b, csr_src, rowptr, aggb);
    gemm_lds<8, 8, 4, 1, 0, 0, 4><<<GB, 256, 0, stream>>>(
        aggb, W2lT, h1b, W2rT, xb, WresT, b2, bres, h2b, nullptr, NN);

    // layer 3 (fused mu+logstd): [mu|logstd] = mean(h2)@[Wmul|Wlsl] + h2@[Wmur|Wlsr] + [bmu|bls]
    aggregate_kernel<256><<<NN / 4, 256, 0, stream>>>(h2b, csr_src, rowptr, aggb);
    gemm_lds<8, 8, 0, 0, 1, 1, 2><<<GB, 128, 0, stream>>>(
        aggb, WcatL, h2b, WcatR, nullptr, nullptr, bmu, bls, out, out + (size_t)NN * 64, NN);
}

// Round 13
// 171.871 us; speedup vs baseline: 1.5351x; 1.0709x over previous
//
#include <hip/hip_runtime.h>
#include <cstddef>

#define NN 20000
#define NE 320000

typedef short bf16x8 __attribute__((ext_vector_type(8)));
typedef float f32x4 __attribute__((ext_vector_type(4)));
typedef unsigned short u16;

__device__ __forceinline__ float bf2f(u16 u) {
    unsigned x = ((unsigned)u) << 16;
    return __builtin_bit_cast(float, x);
}
__device__ __forceinline__ u16 f2bf(float f) {
    unsigned x = __builtin_bit_cast(unsigned, f);
    x = (x + 0x7fff + ((x >> 16) & 1)) >> 16;   // round-to-nearest-even
    return (u16)x;
}

// ---------------- edge-index layout detection (low-contention) ----------------
__global__ __launch_bounds__(256) void detect_kernel(const void* __restrict__ edges, int* flag) {
    __shared__ int bad;
    if (threadIdx.x == 0) bad = 0;
    __syncthreads();
    int any = 0;
    for (int i = blockIdx.x * 256 + threadIdx.x; i < NE; i += 64 * 256) {
        long long v = ((const long long*)edges)[i];
        if (v < 0 || v >= NN) any = 1;
    }
    if (any) bad = 1;               // benign LDS race: all write 1
    __syncthreads();
    if (threadIdx.x == 0 && bad) atomicOr(flag, 1);
}

__global__ __launch_bounds__(256) void convert_kernel(const void* __restrict__ edges,
                                                      const int* __restrict__ flag,
                                                      int* __restrict__ src, int* __restrict__ dst,
                                                      int* __restrict__ deg) {
    int i = blockIdx.x * blockDim.x + threadIdx.x;
    if (i >= NE) return;
    int s, d;
    if (*flag) {
        s = ((const int*)edges)[i];
        d = ((const int*)edges)[NE + i];
    } else {
        s = (int)((const long long*)edges)[i];
        d = (int)((const long long*)edges)[NE + i];
    }
    src[i] = s;
    dst[i] = d;
    atomicAdd(&deg[d], 1);
}

// ---------------- parallel exclusive scan (3 phases) ----------------
__global__ __launch_bounds__(256) void scan1_kernel(const int* __restrict__ deg,
                                                    int* __restrict__ incl, int* __restrict__ bsum) {
    __shared__ int buf[256];
    int t = threadIdx.x, i = blockIdx.x * 256 + t;
    int v = (i < NN) ? deg[i] : 0;
    buf[t] = v;
    __syncthreads();
    for (int off = 1; off < 256; off <<= 1) {
        int u = (t >= off) ? buf[t - off] : 0;
        __syncthreads();
        buf[t] += u;
        __syncthreads();
    }
    if (i < NN) incl[i] = buf[t];
    if (t == 255) bsum[blockIdx.x] = buf[255];
}

__global__ __launch_bounds__(256) void scan2_kernel(const int* __restrict__ bsum,
                                                    int* __restrict__ boff) {
    __shared__ int buf[256];
    const int nb = (NN + 255) / 256;   // 79
    int t = threadIdx.x;
    int v = (t < nb) ? bsum[t] : 0;
    buf[t] = v;
    __syncthreads();
    for (int off = 1; off < 256; off <<= 1) {
        int u = (t >= off) ? buf[t - off] : 0;
        __syncthreads();
        buf[t] += u;
        __syncthreads();
    }
    if (t < nb) boff[t] = buf[t] - v;   // exclusive
}

__global__ __launch_bounds__(256) void scan3_kernel(const int* __restrict__ deg,
                                                    const int* __restrict__ incl,
                                                    const int* __restrict__ boff,
                                                    int* __restrict__ rowptr) {
    int i = blockIdx.x * 256 + threadIdx.x;
    if (i < NN) rowptr[i] = boff[i >> 8] + incl[i] - deg[i];
    if (i == NN) rowptr[NN] = NE;
}

// ---------------- CSR fill ----------------
__global__ __launch_bounds__(256) void fill_kernel(const int* __restrict__ src,
                                                   const int* __restrict__ dst,
                                                   const int* __restrict__ rowptr,
                                                   int* __restrict__ cursor,
                                                   int* __restrict__ csr_src) {
    int i = blockIdx.x * blockDim.x + threadIdx.x;
    if (i >= NE) return;
    int d = dst[i];
    int p = atomicAdd(&cursor[d], 1);
    csr_src[rowptr[d] + p] = src[i];
}

// ---------------- fp32 -> bf16 cast ----------------
__global__ __launch_bounds__(256) void cast_kernel(const float* __restrict__ in,
                                                   u16* __restrict__ out, int n4) {
    int i = blockIdx.x * 256 + threadIdx.x;
    if (i >= n4) return;
    float4 v = *(const float4*)(in + (size_t)i * 4);
    ushort4 o;
    o.x = f2bf(v.x); o.y = f2bf(v.y); o.z = f2bf(v.z); o.w = f2bf(v.w);
    *(ushort4*)(out + (size_t)i * 4) = o;
}

// ---------------- fused weight transpose+cast: 9 jobs in one dispatch ----------------
struct WJobs {
    const float* W[9];
    u16* WT[9];
    int K[9];
    int N[9];
};
__global__ __launch_bounds__(256) void wtrans_all(WJobs jobs) {
    int y = blockIdx.y;
    int K = jobs.K[y], N = jobs.N[y];
    int i = blockIdx.x * 256 + threadIdx.x;
    if (i >= K * N) return;
    int k = i / N, n = i % N;
    jobs.WT[y][(size_t)n * K + k] = f2bf(jobs.W[y][i]);
}

// ---------------- CSR mean-aggregate: 4x-unrolled MLP ----------------
template <int D>
__global__ __launch_bounds__(256) void aggregate_kernel(const u16* __restrict__ feat,
                                                        const int* __restrict__ csr_src,
                                                        const int* __restrict__ rowptr,
                                                        u16* __restrict__ out) {
    int node = blockIdx.x * 4 + (threadIdx.x >> 6);
    if (node >= NN) return;
    int lane = threadIdx.x & 63;
    int beg = rowptr[node], end = rowptr[node + 1];
    int cnt = end - beg;
    float inv = 1.0f / (float)(cnt > 0 ? cnt : 1);

    constexpr int NSUB = (D == 256) ? 2 : 4;
    constexpr int LPG = 64 / NSUB;
    int sub = lane / LPG;
    int c8 = lane % LPG;
    const u16* fc = feat + c8 * 8;

    float a0[8] = {0.f,0.f,0.f,0.f,0.f,0.f,0.f,0.f};
    float a1[8] = {0.f,0.f,0.f,0.f,0.f,0.f,0.f,0.f};

    int e = beg + sub;
    for (; e + 3 * NSUB < end; e += 4 * NSUB) {
        int s0 = csr_src[e];
        int s1 = csr_src[e + NSUB];
        int s2 = csr_src[e + 2 * NSUB];
        int s3 = csr_src[e + 3 * NSUB];
        bf16x8 u0 = *(const bf16x8*)(fc + (size_t)s0 * D);
        bf16x8 u1 = *(const bf16x8*)(fc + (size_t)s1 * D);
        bf16x8 u2 = *(const bf16x8*)(fc + (size_t)s2 * D);
        bf16x8 u3 = *(const bf16x8*)(fc + (size_t)s3 * D);
#pragma unroll
        for (int j = 0; j < 8; j++) {
            a0[j] += bf2f((u16)u0[j]) + bf2f((u16)u2[j]);
            a1[j] += bf2f((u16)u1[j]) + bf2f((u16)u3[j]);
        }
    }
    for (; e < end; e += NSUB) {
        int s = csr_src[e];
        bf16x8 u = *(const bf16x8*)(fc + (size_t)s * D);
#pragma unroll
        for (int j = 0; j < 8; j++) a0[j] += bf2f((u16)u[j]);
    }
#pragma unroll
    for (int j = 0; j < 8; j++) {
        a0[j] += a1[j];
        if (NSUB == 4) a0[j] += __shfl_xor(a0[j], 16);
        a0[j] += __shfl_xor(a0[j], 32);
    }
    if (sub == 0) {
        bf16x8 o;
#pragma unroll
        for (int j = 0; j < 8; j++) o[j] = (short)f2bf(a0[j] * inv);
        *(bf16x8*)(out + (size_t)node * D + c8 * 8) = o;
    }
}

// ---------------- layer-3 final: out = agg(R[:,0:128]) + R[:,128:256] + bias ----------------
// R row: [P_mu(64) | P_ls(64) | Q_mu(64) | Q_ls(64)], P = h2@[Wmul|Wlsl], Q = h2@[Wmur|Wlsr].
// agg commutes with the linear map: agg(h2)@W == agg(h2@W). Gathers only 128 cols/edge.
__global__ __launch_bounds__(256) void agg_final(const u16* __restrict__ R,
                                                 const int* __restrict__ csr_src,
                                                 const int* __restrict__ rowptr,
                                                 const float* __restrict__ bmu,
                                                 const float* __restrict__ bls,
                                                 float* __restrict__ out) {
    int node = blockIdx.x * 4 + (threadIdx.x >> 6);
    if (node >= NN) return;
    int lane = threadIdx.x & 63;
    int beg = rowptr[node], end = rowptr[node + 1];
    int cnt = end - beg;
    float inv = 1.0f / (float)(cnt > 0 ? cnt : 1);

    int sub = lane >> 4;          // 4 edge groups x 16 lanes
    int c8 = lane & 15;           // 16 col-blocks of 8 -> 128 P-cols
    const u16* fc = R + c8 * 8;

    float a0[8] = {0.f,0.f,0.f,0.f,0.f,0.f,0.f,0.f};
    float a1[8] = {0.f,0.f,0.f,0.f,0.f,0.f,0.f,0.f};

    int e = beg + sub;
    for (; e + 12 < end; e += 16) {
        int s0 = csr_src[e];
        int s1 = csr_src[e + 4];
        int s2 = csr_src[e + 8];
        int s3 = csr_src[e + 12];
        bf16x8 u0 = *(const bf16x8*)(fc + (size_t)s0 * 256);
        bf16x8 u1 = *(const bf16x8*)(fc + (size_t)s1 * 256);
        bf16x8 u2 = *(const bf16x8*)(fc + (size_t)s2 * 256);
        bf16x8 u3 = *(const bf16x8*)(fc + (size_t)s3 * 256);
#pragma unroll
        for (int j = 0; j < 8; j++) {
            a0[j] += bf2f((u16)u0[j]) + bf2f((u16)u2[j]);
            a1[j] += bf2f((u16)u1[j]) + bf2f((u16)u3[j]);
        }
    }
    for (; e < end; e += 4) {
        int s = csr_src[e];
        bf16x8 u = *(const bf16x8*)(fc + (size_t)s * 256);
#pragma unroll
        for (int j = 0; j < 8; j++) a0[j] += bf2f((u16)u[j]);
    }
#pragma unroll
    for (int j = 0; j < 8; j++) {
        a0[j] += a1[j];
        a0[j] += __shfl_xor(a0[j], 16);
        a0[j] += __shfl_xor(a0[j], 32);
    }
    if (sub == 0) {
        int c0 = c8 * 8;   // 0..120; all 8 cols in one half
        bf16x8 q = *(const bf16x8*)(R + (size_t)node * 256 + 128 + c0);
        float o[8];
#pragma unroll
        for (int j = 0; j < 8; j++) {
            int c = c0 + j;
            float b = (c < 64) ? bmu[c] : bls[c - 64];
            o[j] = a0[j] * inv + bf2f((u16)q[j]) + b;
        }
        float* dst = (c0 < 64) ? (out + (size_t)node * 64 + c0)
                               : (out + (size_t)NN * 64 + (size_t)node * 64 + (c0 - 64));
        *(float4*)dst = make_float4(o[0], o[1], o[2], o[3]);
        *(float4*)(dst + 4) = make_float4(o[4], o[5], o[6], o[7]);
    }
}

// ---------------- gemm_lds: canonical LDS-staged double-buffered MFMA GEMM ----------------
// Block: 64 rows x NCOL (NCOL = NWAVES*64). Wave w owns 64 rows x 64 cols (4x4 frags).
// K-step = 32; double-buffered LDS; next step's tiles reg-prefetched between barriers.
// Phases: acc += A0@B0 [+ A1@B1] [relu+bias] [+= A2@B2]; epilogue adds badd.
// mfma_f32_16x16x32_bf16 (m89-verified): A/B frag idx=lane&15, k=(lane>>4)*8+j;
// C/D: col=lane&15, row=(lane>>4)*4+reg.
template <int KS0, int KS1, int KS2, int RELU01, int OUT_F32, int NWAVES>
__global__ __launch_bounds__(NWAVES * 64) void gemm_lds(
    const u16* __restrict__ A0, const u16* __restrict__ B0T,
    const u16* __restrict__ A1, const u16* __restrict__ B1T,
    const u16* __restrict__ A2, const u16* __restrict__ B2T,
    const float* __restrict__ bias, const float* __restrict__ bias2,
    void* __restrict__ Cout, int M) {
    constexpr int NT = NWAVES * 64;
    constexpr int NCOL = NWAVES * 64;
    constexpr int AI = 4096 / (NT * 16);
    constexpr int BI = (NCOL * 64) / (NT * 16);
    constexpr int TOT = KS0 + KS1 + KS2;
    constexpr int pS1 = KS0, pS2 = KS0 + KS1;
    constexpr int BOFF = 64 * 32;
    constexpr int BUFSZ = BOFF + NCOL * 32;

    __shared__ __align__(16) u16 smem[2][BUFSZ];

    const int t = threadIdx.x;
    const int w = t >> 6, l = t & 63;
    const int l15 = l & 15, lhi = l >> 4;
    const int rowBase = blockIdx.x * 64;
    const int wc = w * 64;
    const int srow = t >> 2, skk = t & 3;

    f32x4 acc[4][4];
#pragma unroll
    for (int r = 0; r < 4; r++)
#pragma unroll
        for (int n = 0; n < 4; n++) acc[r][n] = f32x4{0.f, 0.f, 0.f, 0.f};

    bf16x8 ar[AI], br[BI];

    auto gload = [&](const u16* __restrict__ A, const u16* __restrict__ BT, int K, int ko) {
#pragma unroll
        for (int i = 0; i < AI; i++) {
            int row = rowBase + i * (NT / 4) + srow;
            row = row < M ? row : M - 1;
            ar[i] = *(const bf16x8*)(A + (size_t)row * K + ko + skk * 8);
        }
#pragma unroll
        for (int i = 0; i < BI; i++) {
            int n = i * (NT / 4) + srow;
            br[i] = *(const bf16x8*)(BT + (size_t)n * K + ko + skk * 8);
        }
    };
    auto swrite = [&](int buf) {
        u16* base = smem[buf];
#pragma unroll
        for (int i = 0; i < AI; i++)
            *(bf16x8*)(base + (size_t)(i * NT + t) * 8) = ar[i];
#pragma unroll
        for (int i = 0; i < BI; i++)
            *(bf16x8*)(base + BOFF + (size_t)(i * NT + t) * 8) = br[i];
    };

    gload(A0, B0T, KS0 * 32, 0);
    int cur = 0;

#pragma unroll 1
    for (int step = 0; step < TOT; step++) {
        __syncthreads();
        swrite(cur);
        int ns = step + 1;
        if (ns < TOT) {
            if (KS2 > 0 && ns >= pS2)       gload(A2, B2T, KS2 * 32, (ns - pS2) * 32);
            else if (KS1 > 0 && ns >= pS1)  gload(A1, B1T, KS1 * 32, (ns - pS1) * 32);
            else                            gload(A0, B0T, KS0 * 32, ns * 32);
        }
        __syncthreads();
        const u16* sb = smem[cur];
        bf16x8 af[4], bf[4];
#pragma unroll
        for (int r = 0; r < 4; r++)
            af[r] = *(const bf16x8*)(sb + (r * 16 + l15) * 32 + lhi * 8);
#pragma unroll
        for (int n = 0; n < 4; n++)
            bf[n] = *(const bf16x8*)(sb + BOFF + (wc + n * 16 + l15) * 32 + lhi * 8);
#pragma unroll
        for (int r = 0; r < 4; r++)
#pragma unroll
            for (int n = 0; n < 4; n++)
                acc[r][n] = __builtin_amdgcn_mfma_f32_16x16x32_bf16(af[r], bf[n], acc[r][n], 0, 0, 0);
        if (RELU01 && step == pS2 - 1) {
#pragma unroll
            for (int n = 0; n < 4; n++) {
                float b = bias[wc + n * 16 + l15];
#pragma unroll
                for (int r = 0; r < 4; r++)
#pragma unroll
                    for (int j = 0; j < 4; j++)
                        acc[r][n][j] = fmaxf(acc[r][n][j] + b, 0.f);
            }
        }
        cur ^= 1;
    }

#pragma unroll
    for (int n = 0; n < 4; n++) {
        int col = wc + n * 16 + l15;
        float badd;
        if constexpr (KS2 > 0)      badd = bias2[col];
        else if constexpr (RELU01)  badd = 0.f;
        else                        badd = bias[col];
#pragma unroll
        for (int r = 0; r < 4; r++) {
#pragma unroll
            for (int j = 0; j < 4; j++) {
                int row = rowBase + r * 16 + lhi * 4 + j;
                if (row >= M) continue;
                float v = acc[r][n][j] + badd;
                if constexpr (OUT_F32) {
                    ((float*)Cout)[(size_t)row * NCOL + col] = v;
                } else {
                    ((u16*)Cout)[(size_t)row * NCOL + col] = f2bf(v);
                }
            }
        }
    }
}

extern "C" void kernel_launch(void* const* d_in, const int* in_sizes, int n_in,
                              void* d_out, int out_size, void* d_ws, size_t ws_size,
                              hipStream_t stream) {
    const float* x    = (const float*)d_in[0];
    const void*  edges = d_in[1];
    const float* W1l  = (const float*)d_in[2];
    const float* b1   = (const float*)d_in[3];
    const float* W1r  = (const float*)d_in[4];
    const float* W2l  = (const float*)d_in[5];
    const float* b2   = (const float*)d_in[6];
    const float* W2r  = (const float*)d_in[7];
    const float* Wres = (const float*)d_in[8];
    const float* bres = (const float*)d_in[9];
    const float* Wmul = (const float*)d_in[10];
    const float* bmu  = (const float*)d_in[11];
    const float* Wmur = (const float*)d_in[12];
    const float* Wlsl = (const float*)d_in[13];
    const float* bls  = (const float*)d_in[14];
    const float* Wlsr = (const float*)d_in[15];
    float* out = (float*)d_out;

    char* ws = (char*)d_ws;
    size_t off = 0;
    // --- contiguous zero-init region (one memset): flag | deg | cursor | zerosf ---
    int*   flag   = (int*)(ws + off); off += 256;
    int*   deg    = (int*)(ws + off); off += (size_t)NN * 4;
    int*   cursor = (int*)(ws + off); off += (size_t)NN * 4;
    float* zerosf = (float*)(ws + off); off += 1024;
    const size_t zlen = off;
    int* src     = (int*)(ws + off); off += (size_t)NE * 4;
    int* dst     = (int*)(ws + off); off += (size_t)NE * 4;
    int* csr_src = (int*)(ws + off); off += (size_t)NE * 4;
    int* rowptr  = (int*)(ws + off); off += (size_t)(NN + 8) * 4;
    int* incl    = (int*)(ws + off); off += (size_t)NN * 4;
    int* bsum    = (int*)(ws + off); off += 256 * 4;
    int* boff    = (int*)(ws + off); off += 256 * 4;
    off = (off + 255) & ~(size_t)255;
    u16* xb    = (u16*)(ws + off); off += (size_t)NN * 128 * 2;
    u16* agg1b = (u16*)(ws + off); off += (size_t)NN * 128 * 2;
    u16* h1b   = (u16*)(ws + off); off += (size_t)NN * 256 * 2;
    u16* h2b   = (u16*)(ws + off); off += (size_t)NN * 256 * 2;
    u16* aggb  = (u16*)(ws + off); off += (size_t)NN * 256 * 2;
    u16* Rb    = (u16*)(ws + off); off += (size_t)NN * 256 * 2;   // layer-3 [P|Q]
    u16* W1lT  = (u16*)(ws + off); off += 128 * 256 * 2;
    u16* W1rT  = (u16*)(ws + off); off += 128 * 256 * 2;
    u16* W2lT  = (u16*)(ws + off); off += 256 * 256 * 2;
    u16* W2rT  = (u16*)(ws + off); off += 256 * 256 * 2;
    u16* WresT = (u16*)(ws + off); off += 128 * 256 * 2;
    u16* Wcat  = (u16*)(ws + off); off += 256 * 256 * 2;   // [Wmul|Wlsl|Wmur|Wlsr]^T

    hipMemsetAsync(flag, 0, zlen, stream);

    const int SB = (NN + 255) / 256;   // 79

    detect_kernel<<<64, 256, 0, stream>>>(edges, flag);
    convert_kernel<<<NE / 256, 256, 0, stream>>>(edges, flag, src, dst, deg);
    scan1_kernel<<<SB, 256, 0, stream>>>(deg, incl, bsum);
    scan2_kernel<<<1, 256, 0, stream>>>(bsum, boff);
    scan3_kernel<<<SB, 256, 0, stream>>>(deg, incl, boff, rowptr);
    fill_kernel<<<NE / 256, 256, 0, stream>>>(src, dst, rowptr, cursor, csr_src);

    cast_kernel<<<(NN * 128 / 4 + 255) / 256, 256, 0, stream>>>(x, xb, NN * 128 / 4);

    WJobs jobs;
    jobs.W[0] = W1l;  jobs.WT[0] = W1lT;           jobs.K[0] = 128; jobs.N[0] = 256;
    jobs.W[1] = W1r;  jobs.WT[1] = W1rT;           jobs.K[1] = 128; jobs.N[1] = 256;
    jobs.W[2] = W2l;  jobs.WT[2] = W2lT;           jobs.K[2] = 256; jobs.N[2] = 256;
    jobs.W[3] = W2r;  jobs.WT[3] = W2rT;           jobs.K[3] = 256; jobs.N[3] = 256;
    jobs.W[4] = Wres; jobs.WT[4] = WresT;          jobs.K[4] = 128; jobs.N[4] = 256;
    jobs.W[5] = Wmul; jobs.WT[5] = Wcat;           jobs.K[5] = 256; jobs.N[5] = 64;
    jobs.W[6] = Wlsl; jobs.WT[6] = Wcat + 64*256;  jobs.K[6] = 256; jobs.N[6] = 64;
    jobs.W[7] = Wmur; jobs.WT[7] = Wcat + 128*256; jobs.K[7] = 256; jobs.N[7] = 64;
    jobs.W[8] = Wlsr; jobs.WT[8] = Wcat + 192*256; jobs.K[8] = 256; jobs.N[8] = 64;
    wtrans_all<<<dim3(256, 9), 256, 0, stream>>>(jobs);

    const int GB = (NN + 63) / 64;   // 313

    // layer 1: h1 = relu(mean(x)@W1l + x@W1r + b1)
    aggregate_kernel<128><<<NN / 4, 256, 0, stream>>>(xb, csr_src, rowptr, agg1b);
    gemm_lds<4, 4, 0, 1, 0, 4><<<GB, 256, 0, stream>>>(
        agg1b, W1lT, xb, W1rT, nullptr, nullptr, b1, nullptr, h1b, NN);

    // layer 2 (fused residual): h2 = relu(mean(h1)@W2l + h1@W2r + b2) + x@Wres + bres
    aggregate_kernel<256><<<NN / 4, 256, 0, stream>>>(h1b, csr_src, rowptr, aggb);
    gemm_lds<8, 8, 4, 1, 0, 4><<<GB, 256, 0, stream>>>(
        aggb, W2lT, h1b, W2rT, xb, WresT, b2, bres, h2b, NN);

    // layer 3 (agg-after-GEMM via linearity): R = h2@[Wmul|Wlsl|Wmur|Wlsr];
    // out = agg(R[:,0:128]) + R[:,128:256] + [bmu|bls]
    gemm_lds<8, 0, 0, 0, 0, 4><<<GB, 256, 0, stream>>>(
        h2b, Wcat, nullptr, nullptr, nullptr, nullptr, zerosf, nullptr, Rb, NN);
    agg_final<<<NN / 4, 256, 0, stream>>>(Rb, csr_src, rowptr, bmu, bls, out);
}